// Round 1
// baseline (340.798 us; speedup 1.0000x reference)
//
#include <hip/hip_runtime.h>

// B=16384, N=54, D_IN=64, D_HID=4, D_OUT=256
// out[b][o] = bf[o] + sum_c relu( xWc + sum_k nbWd + bias )[b][c] * Wf[o][c]
//
// Fused single kernel:
//  Phase 1: each 16-thread group computes one position's 4 hidden values.
//           Combined weight tensor W[4][448] staged in LDS (Wc ++ Wd).
//  Phase 2: thread tid computes output column tid for all RB rows.

#define N_POS   54
#define D_OUT   256
#define RB      8                 // batch rows per block
#define NPB     (RB * N_POS)      // 432 positions per block
#define THREADS 256
#define GROUPS  (THREADS / 16)    // 16 position-groups per block
#define ITERS   (NPB / GROUPS)    // 27

__global__ __launch_bounds__(THREADS)
void hexconv_fc_kernel(const float* __restrict__ x,
                       const float* __restrict__ nb,
                       const float* __restrict__ Wc,
                       const float* __restrict__ bc,
                       const float* __restrict__ Wd,
                       const float* __restrict__ bd,
                       const float* __restrict__ Wf,
                       const float* __restrict__ bf,
                       float* __restrict__ out)
{
    // combined weights: wlds4[hh*112 + f], f<16 -> Wc row hh, f>=16 -> Wd[k][hh]
    __shared__ float4 wlds4[4 * 112];              // 7168 B
    __shared__ __align__(16) float hlds[RB * 216]; // 6912 B

    const int tid = threadIdx.x;
    const int b0  = blockIdx.x * RB;

    // ---- stage combined weights into LDS ----
    const float4* Wc4 = (const float4*)Wc;   // [4][16]
    const float4* Wd4 = (const float4*)Wd;   // [6][4][16]
    for (int idx = tid; idx < 4 * 112; idx += THREADS) {
        const int hh = idx / 112;
        const int f  = idx - hh * 112;
        float4 v;
        if (f < 16) {
            v = Wc4[hh * 16 + f];
        } else {
            const int k  = (f - 16) >> 4;
            const int d4 = (f - 16) & 15;
            v = Wd4[(k * 4 + hh) * 16 + d4];
        }
        wlds4[idx] = v;
    }

    // ---- bias: bc[hh] + sum_k bd[k][hh] (tiny, all-thread redundant) ----
    float bias[4];
#pragma unroll
    for (int hh = 0; hh < 4; ++hh) {
        float s = bc[hh];
#pragma unroll
        for (int k = 0; k < 6; ++k) s += bd[k * 4 + hh];
        bias[hh] = s;
    }

    __syncthreads();

    // ---- phase 1: HexConv ----
    const int g = tid >> 4;       // group 0..15
    const int t = tid & 15;       // lane in group
    const float4* x4  = (const float4*)x;    // [pos][16]
    const float4* nb4 = (const float4*)nb;   // [pos][96]

    for (int it = 0; it < ITERS; ++it) {
        const int p = it * GROUPS + g;        // local position 0..431
        const int r = p / N_POS;
        const int n = p - r * N_POS;
        const int posIdx = (b0 + r) * N_POS + n;

        float4 data[7];
        data[0] = x4[posIdx * 16 + t];
#pragma unroll
        for (int j = 1; j < 7; ++j)
            data[j] = nb4[posIdx * 96 + (t + 16 * (j - 1))];

        float acc[4] = {0.f, 0.f, 0.f, 0.f};
#pragma unroll
        for (int j = 0; j < 7; ++j) {
            const float4 d = data[j];
#pragma unroll
            for (int hh = 0; hh < 4; ++hh) {
                const float4 w = wlds4[hh * 112 + t + 16 * j];
                acc[hh] += d.x * w.x + d.y * w.y + d.z * w.z + d.w * w.w;
            }
        }

        // reduce across the 16-lane group
#pragma unroll
        for (int hh = 0; hh < 4; ++hh) {
#pragma unroll
            for (int m = 1; m <= 8; m <<= 1)
                acc[hh] += __shfl_xor(acc[hh], m, 64);
        }

        if (t < 4) {
            const float v = acc[t] + bias[t];
            hlds[p * 4 + t] = v > 0.f ? v : 0.f;
        }
    }

    __syncthreads();

    // ---- phase 2: FC. thread tid -> output column tid, all RB rows ----
    const float4* Wf4 = (const float4*)Wf;     // [256][54]
    const float4* h4  = (const float4*)hlds;   // [RB][54]

    float acc2[RB];
#pragma unroll
    for (int r2 = 0; r2 < RB; ++r2) acc2[r2] = 0.f;

    for (int c4 = 0; c4 < 54; ++c4) {
        const float4 w = Wf4[tid * 54 + c4];
#pragma unroll
        for (int r2 = 0; r2 < RB; ++r2) {
            const float4 hv = h4[r2 * 54 + c4];
            acc2[r2] += hv.x * w.x + hv.y * w.y + hv.z * w.z + hv.w * w.w;
        }
    }

    const float bfv = bf[tid];
#pragma unroll
    for (int r2 = 0; r2 < RB; ++r2)
        out[(b0 + r2) * D_OUT + tid] = acc2[r2] + bfv;
}

extern "C" void kernel_launch(void* const* d_in, const int* in_sizes, int n_in,
                              void* d_out, int out_size, void* d_ws, size_t ws_size,
                              hipStream_t stream) {
    const float* x  = (const float*)d_in[0];
    const float* nb = (const float*)d_in[1];
    const float* Wc = (const float*)d_in[2];
    const float* bc = (const float*)d_in[3];
    const float* Wd = (const float*)d_in[4];
    const float* bd = (const float*)d_in[5];
    const float* Wf = (const float*)d_in[6];
    const float* bf = (const float*)d_in[7];
    float* out = (float*)d_out;

    const int B = 16384;
    dim3 grid(B / RB), block(THREADS);
    hexconv_fc_kernel<<<grid, block, 0, stream>>>(x, nb, Wc, bc, Wd, bd, Wf, bf, out);
}

// Round 2
// 306.989 us; speedup vs baseline: 1.1101x; 1.1101x over previous
//
#include <hip/hip_runtime.h>

// B=16384, N=54, D_IN=64, D_HID=4, D_OUT=256
// Fully-fused, FC interleaved into the hexconv stream so the FC's LDS/VALU
// work hides under the HBM-bound neighbor stream (no phase-2 tail).
//
// Block = 256 threads, handles CHUNKS=2 consecutive row-chunks of RB=8 batch
// rows. 16 groups of 16 lanes; group g -> (batch row r=g>>1, col n=2*it+(g&1)).
// Per iter: each group computes one position's 4 hidden values (dot over 448
// inputs, 16-lane shfl reduce), writes h float4 to a 512B double-buffered LDS
// slab, one barrier, then every thread (= output col) accumulates
// acc2[r] += h[r][n] . Wf[col][n] for the 16 fresh (r,n) pairs.
// Grid = 1024 blocks -> 4 blocks/CU co-resident (launch_bounds caps VGPR<=128),
// no partial-round tail.

#define N_POS   54
#define D_OUT   256
#define RB      8
#define THREADS 256
#define ITERS   27        // N_POS / 2
#define CHUNKS  2

__global__ __launch_bounds__(THREADS, 4)
void hexconv_fc_kernel(const float* __restrict__ x,
                       const float* __restrict__ nb,
                       const float* __restrict__ Wc,
                       const float* __restrict__ bc,
                       const float* __restrict__ Wd,
                       const float* __restrict__ bd,
                       const float* __restrict__ Wf,
                       const float* __restrict__ bf,
                       float* __restrict__ out)
{
    // combined weights: wlds4[hh*112 + f], f<16 -> Wc row hh, f>=16 -> Wd[k][hh]
    __shared__ float4 wlds4[4 * 112];   // 7168 B
    __shared__ float4 hbuf[2][16];      // [buf][g] : h for (r=g>>1, half=g&1)

    const int tid = threadIdx.x;

    // ---- stage combined weights into LDS ----
    const float4* Wc4 = (const float4*)Wc;   // [4][16]
    const float4* Wd4 = (const float4*)Wd;   // [6][4][16]
    for (int idx = tid; idx < 4 * 112; idx += THREADS) {
        const int hh = idx / 112;
        const int f  = idx - hh * 112;
        float4 v;
        if (f < 16) {
            v = Wc4[hh * 16 + f];
        } else {
            const int k  = (f - 16) >> 4;
            const int d4 = (f - 16) & 15;
            v = Wd4[(k * 4 + hh) * 16 + d4];
        }
        wlds4[idx] = v;
    }

    // ---- bias: bc[hh] + sum_k bd[k][hh] ----
    float bias[4];
#pragma unroll
    for (int hh = 0; hh < 4; ++hh) {
        float s = bc[hh];
#pragma unroll
        for (int k = 0; k < 6; ++k) s += bd[k * 4 + hh];
        bias[hh] = s;
    }

    const int g  = tid >> 4;      // group 0..15
    const int t  = tid & 15;      // lane in group
    const int r  = g >> 1;        // batch row within chunk 0..7
    const int nh = g & 1;         // column half

    const float4* x4   = (const float4*)x;    // [pos][16]
    const float4* nb4  = (const float4*)nb;   // [pos][96]
    const float4* wfRow = (const float4*)Wf + tid * 54;   // this col's Wf row
    const float   bfv  = bf[tid];

    __syncthreads();

    for (int c = 0; c < CHUNKS; ++c) {
        const int b0 = (blockIdx.x * CHUNKS + c) * RB;
        const long rowBase = (long)(b0 + r) * N_POS;

        float acc2[RB];
#pragma unroll
        for (int r2 = 0; r2 < RB; ++r2) acc2[r2] = 0.f;

        for (int it = 0; it < ITERS; ++it) {
            const int n = 2 * it + nh;
            const long posIdx = rowBase + n;

            float4 data[7];
            data[0] = x4[posIdx * 16 + t];
#pragma unroll
            for (int j = 1; j < 7; ++j)
                data[j] = nb4[posIdx * 96 + (t + 16 * (j - 1))];

            float acc[4] = {0.f, 0.f, 0.f, 0.f};
#pragma unroll
            for (int j = 0; j < 7; ++j) {
                const float4 d = data[j];
#pragma unroll
                for (int hh = 0; hh < 4; ++hh) {
                    const float4 w = wlds4[hh * 112 + t + 16 * j];
                    acc[hh] += d.x * w.x + d.y * w.y + d.z * w.z + d.w * w.w;
                }
            }

            // 16-lane group reduce (masks 1..8 stay inside the group)
#pragma unroll
            for (int hh = 0; hh < 4; ++hh) {
#pragma unroll
                for (int m = 1; m <= 8; m <<= 1)
                    acc[hh] += __shfl_xor(acc[hh], m, 64);
            }

            const int cur = it & 1;
            if (t < 4) {
                const float v = acc[t] + bias[t];
                ((float*)&hbuf[cur][g])[t] = v > 0.f ? v : 0.f;
            }
            __syncthreads();

            // ---- interleaved FC: this thread = output column tid ----
            const float4 w0 = wfRow[2 * it];
            const float4 w1 = wfRow[2 * it + 1];
#pragma unroll
            for (int g2 = 0; g2 < 16; ++g2) {
                const float4 hv = hbuf[cur][g2];
                const float4 w  = (g2 & 1) ? w1 : w0;
                acc2[g2 >> 1] += hv.x * w.x + hv.y * w.y + hv.z * w.z + hv.w * w.w;
            }
        }

        const long outBase = (long)b0 * D_OUT + tid;
#pragma unroll
        for (int r2 = 0; r2 < RB; ++r2)
            out[outBase + (long)r2 * D_OUT] = acc2[r2] + bfv;
    }
}

extern "C" void kernel_launch(void* const* d_in, const int* in_sizes, int n_in,
                              void* d_out, int out_size, void* d_ws, size_t ws_size,
                              hipStream_t stream) {
    const float* x  = (const float*)d_in[0];
    const float* nb = (const float*)d_in[1];
    const float* Wc = (const float*)d_in[2];
    const float* bc = (const float*)d_in[3];
    const float* Wd = (const float*)d_in[4];
    const float* bd = (const float*)d_in[5];
    const float* Wf = (const float*)d_in[6];
    const float* bf = (const float*)d_in[7];
    float* out = (float*)d_out;

    const int B = 16384;
    dim3 grid(B / (RB * CHUNKS)), block(THREADS);
    hexconv_fc_kernel<<<grid, block, 0, stream>>>(x, nb, Wc, bc, Wd, bd, Wf, bf, out);
}